// Round 9
// baseline (235.084 us; speedup 1.0000x reference)
//
#include <hip/hip_runtime.h>
#include <hip/hip_bf16.h>

typedef unsigned short u16;
typedef float f32x4 __attribute__((ext_vector_type(4)));
typedef __bf16 bf16x8 __attribute__((ext_vector_type(8)));

#define NB 4096     // batch rows
#define NM 16384    // memory bank rows
#define ND 256      // feature dim (K)
#define CT 160      // col tiles (20480 / 128)
#define RT 16       // row tiles (4096 / 256)

__device__ __forceinline__ u16 f2bf(float x) {
    unsigned u = __float_as_uint(x);
    u += 0x7FFF + ((u >> 16) & 1);   // round-to-nearest-even
    return (u16)(u >> 16);
}

__device__ __forceinline__ float ex2(float x) {
#if __has_builtin(__builtin_amdgcn_exp2f)
    return __builtin_amdgcn_exp2f(x);   // single v_exp_f32
#else
    return exp2f(x);
#endif
}

// DPP lane moves within a row of 16 (our reduction group = lane16, q = DPP row)
template<int C>
__device__ __forceinline__ float dppf(float x) {
    int v = __float_as_int(x);
    return __int_as_float(__builtin_amdgcn_update_dpp(v, v, C, 0xF, 0xF, false));
}
template<int C>
__device__ __forceinline__ unsigned dppu(unsigned x) {
    return (unsigned)__builtin_amdgcn_update_dpp((int)x, (int)x, C, 0xF, 0xF, false);
}
#define DPP_XOR1 0xB1   // quad_perm [1,0,3,2]
#define DPP_XOR2 0x4E   // quad_perm [2,3,0,1]
#define DPP_ROR4 0x124  // row_ror:4
#define DPP_ROR8 0x128  // row_ror:8

__device__ __forceinline__ void gld_lds16(const u16* g, u16* l) {
    __builtin_amdgcn_global_load_lds((__attribute__((address_space(1))) void*)g,
                                     (__attribute__((address_space(3))) void*)l,
                                     16, 0, 0);
}

// ---- fused prep: normalize f1/f2, convert banks to bf16, zero accumulators -
__global__ __launch_bounds__(256) void prep(
    const float* __restrict__ if1, const float* __restrict__ if2,
    const float* __restrict__ mb1, const float* __restrict__ mb2,
    float* __restrict__ f1f, float* __restrict__ f2f,
    u16* __restrict__ f1n, u16* __restrict__ f2n,
    u16* __restrict__ mb1n, u16* __restrict__ mb2n,
    unsigned* __restrict__ Mpack, float* __restrict__ accum)
{
    const int b = blockIdx.x, t = threadIdx.x;
    if (b == 0 && t < 8) accum[t] = 0.f;        // sums + counter
    if (b < 32) Mpack[b * 256 + t] = 0u;        // [2*NB] = 8192 for atomicMax
    if (b < 2048) {
        const int wave = t >> 6, lane = t & 63;
        const int g = b * 4 + wave;         // 0..8191
        const float* in; float* of; u16* ob; int row;
        if (g < NB) { in = if1; of = f1f; ob = f1n; row = g; }
        else        { in = if2; of = f2f; ob = f2n; row = g - NB; }
        float4 v = ((const float4*)(in + (size_t)row * ND))[lane];
        float ss = v.x*v.x + v.y*v.y + v.z*v.z + v.w*v.w;
        #pragma unroll
        for (int off = 1; off < 64; off <<= 1) ss += __shfl_xor(ss, off, 64);
        float inv = 1.0f / fmaxf(sqrtf(ss), 1e-12f);
        float4 o = make_float4(v.x*inv, v.y*inv, v.z*inv, v.w*inv);
        ((float4*)(of + (size_t)row * ND))[lane] = o;
        ushort4 bb = make_ushort4(f2bf(o.x), f2bf(o.y), f2bf(o.z), f2bf(o.w));
        ((ushort4*)(ob + (size_t)row * ND))[lane] = bb;
    } else {
        size_t i = (size_t)(b - 2048) * 256 + t;      // float4 index
        const float* in; u16* ob; size_t idx;
        if (i < (size_t)NM * 64) { in = mb1; ob = mb1n; idx = i; }
        else { in = mb2; ob = mb2n; idx = i - (size_t)NM * 64; }
        float4 v = ((const float4*)in)[idx];
        ushort4 bb = make_ushort4(f2bf(v.x), f2bf(v.y), f2bf(v.z), f2bf(v.w));
        ((ushort4*)ob)[idx] = bb;
    }
}

// ---- fused GEMM + (sum-exp, packed max/argmax) epilogue --------------------
// grid: (160 coltiles, 16 rowtiles, 2 matmuls), block 256 (4 waves).
// Block tile 256x128; wave tile 128x64 (wr=wave>>1 row half, wc=wave&1 col
// half) -> 0.73x LDS fragment bytes/MAC and 0.75x staging traffic vs 64x64.
// LDS: As 32K + Bs 16K = 48K -> 3 blocks/CU at launch_bounds(256,3)
// (170-reg budget; acc 128 + frags ~20 + misc fits. (256,4+) would spill).
// XOR-swizzled LDS chunks; Z via coalesced Zpart stores; max/argmax via one
// atomicMax/row: pack=(bits(t+bias)&0xFFFFC000)|(16383-gcol).
__global__ __launch_bounds__(256, 3) void gemm_nce(
    const u16* __restrict__ f1n, const u16* __restrict__ f2n,
    const u16* __restrict__ mb1n, const u16* __restrict__ mb2n,
    const float* __restrict__ scale_ptr,
    float* __restrict__ Zpart,      // [2][CT][NB]
    unsigned* __restrict__ Mpack)   // [2][NB]
{
    __shared__ __attribute__((aligned(16))) u16 As[256 * 64];   // 32 KB
    __shared__ __attribute__((aligned(16))) u16 Bs[128 * 64];   // 16 KB
    // reduction scratch aliases As (dead after K-loop tail barrier): 4 KB
    float    (*redsum)[256] = (float(*)[256])As;
    unsigned (*redpak)[256] = (unsigned(*)[256])(As + 1024);

    const int ctile = blockIdx.x, rtile = blockIdx.y, z = blockIdx.z;
    const u16* A  = (z ? f2n : f1n) + (size_t)rtile * 256 * ND;
    const u16* Bp = (ctile < 32) ? ((z ? f1n : f2n) + (size_t)ctile * 128 * ND)
                                 : ((z ? mb1n : mb2n) + (size_t)(ctile - 32) * 128 * ND);
    const int t = threadIdx.x;
    const int wave = t >> 6, lane = t & 63;
    const int wr = wave >> 1, wc = wave & 1;
    const int lane16 = lane & 15, q = lane >> 4;
    const int srow = t >> 3;                        // 0..31 staged row
    const int cg = (t & 7) ^ ((t >> 3) & 7);        // swizzled global chunk

    f32x4 acc[8][4] = {};

    #pragma unroll
    for (int kt = 0; kt < 4; ++kt) {
        const u16* ga = A  + (size_t)srow * ND + kt * 64 + cg * 8;
        const u16* gb = Bp + (size_t)srow * ND + kt * 64 + cg * 8;
        u16* la = As + t * 8;
        u16* lb = Bs + t * 8;
        #pragma unroll
        for (int ch = 0; ch < 8; ++ch)      // A: 256 rows, 32-row strides
            gld_lds16(ga + (size_t)ch * 32 * ND, la + ch * 2048);
        #pragma unroll
        for (int ch = 0; ch < 4; ++ch)      // B: 128 rows
            gld_lds16(gb + (size_t)ch * 32 * ND, lb + ch * 2048);
        __syncthreads();   // drains vmcnt (global_load_lds) before LDS reads
        #pragma unroll
        for (int kk = 0; kk < 2; ++kk) {
            const int sw = (kk * 4 + q) ^ (lane16 & 7);   // swizzled chunk slot
            bf16x8 bfr[4];
            #pragma unroll
            for (int j = 0; j < 4; ++j)
                bfr[j] = *(const bf16x8*)(Bs + (wc*64 + j*16 + lane16)*64 + sw*8);
            #pragma unroll
            for (int i = 0; i < 8; ++i) {
                bf16x8 af = *(const bf16x8*)(As + (wr*128 + i*16 + lane16)*64 + sw*8);
                #pragma unroll
                for (int j = 0; j < 4; ++j)
                    acc[i][j] = __builtin_amdgcn_mfma_f32_16x16x32_bf16(
                        af, bfr[j], acc[i][j], 0, 0, 0);
            }
        }
        __syncthreads();
    }
    // As now dead as tile storage; redsum/redpak live in it from here on.

    const float scale = *scale_ptr;
    const float kl = scale * 1.44269504088896f;  // scale * log2(e)
    const float bias = kl + 1.0f;                // t+bias in [1, 2kl+1] > 0
    const bool doicel = (ctile >= 32);

    unsigned cpack[4];
    #pragma unroll
    for (int j = 0; j < 4; ++j) cpack[j] = 127 - (j * 16 + lane16);

    // C/D layout (m89/m91): col = lane&15, row = q*4 + reg (within 16x16)
    #pragma unroll
    for (int i = 0; i < 8; ++i) {
        #pragma unroll
        for (int r = 0; r < 4; ++r) {
            float t0 = kl * acc[i][0][r], t1 = kl * acc[i][1][r],
                  t2 = kl * acc[i][2][r], t3 = kl * acc[i][3][r];
            float e = (ex2(t0) + ex2(t1)) + (ex2(t2) + ex2(t3));
            e += dppf<DPP_XOR1>(e);
            e += dppf<DPP_XOR2>(e);
            e += dppf<DPP_ROR4>(e);
            e += dppf<DPP_ROR8>(e);
            unsigned p = 0;
            if (doicel) {
                unsigned p0 = (__float_as_uint(t0 + bias) & 0xFFFFFF80u) | cpack[0];
                unsigned p1 = (__float_as_uint(t1 + bias) & 0xFFFFFF80u) | cpack[1];
                unsigned p2 = (__float_as_uint(t2 + bias) & 0xFFFFFF80u) | cpack[2];
                unsigned p3 = (__float_as_uint(t3 + bias) & 0xFFFFFF80u) | cpack[3];
                p = max(max(p0, p1), max(p2, p3));
                p = max(p, dppu<DPP_XOR1>(p));
                p = max(p, dppu<DPP_XOR2>(p));
                p = max(p, dppu<DPP_ROR4>(p));
                p = max(p, dppu<DPP_ROR8>(p));
            }
            if (lane16 == 0) {
                int rl = wr*128 + i*16 + q*4 + r;
                redsum[wc][rl] = e;
                redpak[wc][rl] = p;
            }
        }
    }
    __syncthreads();
    {
        int grow = rtile * 256 + t;
        Zpart[((size_t)z * CT + ctile) * NB + grow] = redsum[0][t] + redsum[1][t];
        if (doicel) {
            unsigned q0 = redpak[0][t], q1 = redpak[1][t];
            int c0 = 127 - (int)(q0 & 127);   // col within wc=0 half (0..63)
            int c1 = 127 - (int)(q1 & 127);
            int cb = (ctile - 32) * 128;
            unsigned g0 = (q0 & 0xFFFFC000u) | (unsigned)(16383 - (cb + c0));
            unsigned g1 = (q1 & 0xFFFFC000u) | (unsigned)(16383 - (cb + 64 + c1));
            unsigned g = g0 > g1 ? g0 : g1;   // equal-val tie -> lower gcol wins
            atomicMax(&Mpack[z * NB + grow], g);
        }
    }
}

// ---- finalize: Z-reduce + decode argmax + gather + MSE/CE + combine --------
// 256 blocks x 256 threads: 16 rows/block.
__global__ __launch_bounds__(256) void finalize4(
    const float* __restrict__ Zpart, const unsigned* __restrict__ Mpack,
    const float* __restrict__ f1f, const float* __restrict__ f2f,
    const float* __restrict__ mb1, const float* __restrict__ mb2,
    const float* __restrict__ scale_ptr, float* __restrict__ accum,
    float* __restrict__ out)
{
    __shared__ float zp[2][16][16];   // [z][cidx][row_l]
    __shared__ float Zr[2][16];
    __shared__ float lds5[16][5];
    const int t = threadIdx.x, g = t >> 4, l16 = t & 15;
    const int base = blockIdx.x * 16;

    // Phase A: Z partial sums, coalesced (lanes along rows)
    {
        const int row_l = t & 15, cidx = t >> 4;
        #pragma unroll
        for (int z = 0; z < 2; ++z) {
            float s = 0.f;
            #pragma unroll
            for (int c = cidx * 10; c < cidx * 10 + 10; ++c)
                s += Zpart[((size_t)z * CT + c) * NB + base + row_l];
            zp[z][cidx][row_l] = s;
        }
    }
    __syncthreads();
    if (t < 32) {
        int z = t >> 4, rl = t & 15;
        float s = 0.f;
        #pragma unroll
        for (int k = 0; k < 16; ++k) s += zp[z][k][rl];
        Zr[z][rl] = s;
    }
    __syncthreads();

    const int row = base + g;
    const float scale = *scale_ptr;
    const float kl = scale * 1.44269504088896f;
    const float bias = kl + 1.0f;

    unsigned mp1 = Mpack[row], mp2 = Mpack[NB + row];
    int a1 = 16383 - (int)(mp1 & 16383u);
    int a2 = 16383 - (int)(mp2 & 16383u);
    float m1 = (__uint_as_float(mp1 & 0xFFFFC000u) - bias) / kl;
    float m2 = (__uint_as_float(mp2 & 0xFFFFC000u) - bias) / kl;

    const float4* x1p = (const float4*)(f1f + (size_t)row * ND);
    const float4* x2p = (const float4*)(f2f + (size_t)row * ND);
    const float4* y1p = (const float4*)(mb2 + (size_t)a1 * ND);
    const float4* y2p = (const float4*)(mb1 + (size_t)a2 * ND);
    float d = 0.f, sq1 = 0.f, sq2 = 0.f;
    #pragma unroll
    for (int k = 0; k < 4; ++k) {
        int idx = k * 16 + l16;
        float4 x1 = x1p[idx], x2 = x2p[idx], y1 = y1p[idx], y2 = y2p[idx];
        d += x1.x*x2.x + x1.y*x2.y + x1.z*x2.z + x1.w*x2.w;
        float dx = x1.x-y1.x, dy = x1.y-y1.y, dz = x1.z-y1.z, dw = x1.w-y1.w;
        sq1 += dx*dx + dy*dy + dz*dz + dw*dw;
        dx = x2.x-y2.x; dy = x2.y-y2.y; dz = x2.z-y2.z; dw = x2.w-y2.w;
        sq2 += dx*dx + dy*dy + dz*dz + dw*dw;
    }
    #pragma unroll
    for (int off = 1; off < 16; off <<= 1) {
        d   += __shfl_xor(d,   off, 16);
        sq1 += __shfl_xor(sq1, off, 16);
        sq2 += __shfl_xor(sq2, off, 16);
    }
    if (l16 == 0) {
        bool k1 = m1 > 0.2f, k2 = m2 > 0.2f;
        lds5[g][0] = logf(Zr[0][g]) + logf(Zr[1][g]) - 2.f * scale * d;
        lds5[g][1] = k1 ? sq1 : 0.f;
        lds5[g][2] = k1 ? 1.f : 0.f;
        lds5[g][3] = k2 ? sq2 : 0.f;
        lds5[g][4] = k2 ? 1.f : 0.f;
    }
    __syncthreads();
    if (t < 5) {
        float s = 0.f;
        #pragma unroll
        for (int r = 0; r < 16; ++r) s += lds5[r][t];
        atomicAdd(&accum[t], s);
    }
    __syncthreads();
    if (t == 0) {
        __threadfence();
        int old = atomicAdd((int*)(accum + 5), 1);
        if (old == (int)gridDim.x - 1) {        // last block: combine
            __threadfence();
            float a0 = atomicAdd(&accum[0], 0.f);
            float a1v = atomicAdd(&accum[1], 0.f);
            float a2v = atomicAdd(&accum[2], 0.f);
            float a3v = atomicAdd(&accum[3], 0.f);
            float a4v = atomicAdd(&accum[4], 0.f);
            float nce = 0.5f * a0 / (float)NB;
            float icel1 = a2v > 0.f ? a1v / (a2v * (float)ND) : 0.f;
            float icel2 = a4v > 0.f ? a3v / (a4v * (float)ND) : 0.f;
            out[0] = nce + 0.25f * (icel1 + icel2);   // LAMBDA_ICEL = 0.5
        }
    }
}

extern "C" void kernel_launch(void* const* d_in, const int* in_sizes, int n_in,
                              void* d_out, int out_size, void* d_ws, size_t ws_size,
                              hipStream_t stream) {
    const float* if1   = (const float*)d_in[0];
    const float* if2   = (const float*)d_in[1];
    const float* scale = (const float*)d_in[2];
    const float* mb1   = (const float*)d_in[3];
    const float* mb2   = (const float*)d_in[4];
    float* out = (float*)d_out;

    unsigned char* w = (unsigned char*)d_ws;
    size_t off = 0;
    auto alloc = [&](size_t bytes) {
        void* p = w + off;
        off += (bytes + 255) & ~(size_t)255;
        return p;
    };
    u16*      f1n   = (u16*)     alloc((size_t)NB * ND * 2);
    u16*      f2n   = (u16*)     alloc((size_t)NB * ND * 2);
    u16*      mb1n  = (u16*)     alloc((size_t)NM * ND * 2);
    u16*      mb2n  = (u16*)     alloc((size_t)NM * ND * 2);
    float*    f1f   = (float*)   alloc((size_t)NB * ND * 4);
    float*    f2f   = (float*)   alloc((size_t)NB * ND * 4);
    float*    Zpart = (float*)   alloc((size_t)2 * CT * NB * 4);
    unsigned* Mpack = (unsigned*)alloc((size_t)2 * NB * 4);
    float*    accum = (float*)   alloc(256);

    prep<<<dim3(10240), 256, 0, stream>>>(if1, if2, mb1, mb2,
                                          f1f, f2f, f1n, f2n, mb1n, mb2n,
                                          Mpack, accum);
    gemm_nce<<<dim3(CT, RT, 2), 256, 0, stream>>>(f1n, f2n, mb1n, mb2n, scale,
                                                  Zpart, Mpack);
    finalize4<<<dim3(NB / 16), 256, 0, stream>>>(Zpart, Mpack,
                                                 f1f, f2f, mb1, mb2, scale,
                                                 accum, out);
}

// Round 10
// 209.676 us; speedup vs baseline: 1.1212x; 1.1212x over previous
//
#include <hip/hip_runtime.h>
#include <hip/hip_bf16.h>

typedef unsigned short u16;
typedef float f32x4 __attribute__((ext_vector_type(4)));
typedef __bf16 bf16x8 __attribute__((ext_vector_type(8)));

#define NB 4096     // batch rows
#define NM 16384    // memory bank rows
#define ND 256      // feature dim (K)
#define CT 160      // col tiles (20480 / 128)
#define RT 16       // row tiles (4096 / 256)

__device__ __forceinline__ u16 f2bf(float x) {
    unsigned u = __float_as_uint(x);
    u += 0x7FFF + ((u >> 16) & 1);   // round-to-nearest-even
    return (u16)(u >> 16);
}

__device__ __forceinline__ float ex2(float x) {
#if __has_builtin(__builtin_amdgcn_exp2f)
    return __builtin_amdgcn_exp2f(x);   // single v_exp_f32
#else
    return exp2f(x);
#endif
}

// DPP lane moves within a row of 16 (our reduction group = lane16, q = DPP row)
template<int C>
__device__ __forceinline__ float dppf(float x) {
    int v = __float_as_int(x);
    return __int_as_float(__builtin_amdgcn_update_dpp(v, v, C, 0xF, 0xF, false));
}
template<int C>
__device__ __forceinline__ unsigned dppu(unsigned x) {
    return (unsigned)__builtin_amdgcn_update_dpp((int)x, (int)x, C, 0xF, 0xF, false);
}
#define DPP_XOR1 0xB1   // quad_perm [1,0,3,2]
#define DPP_XOR2 0x4E   // quad_perm [2,3,0,1]
#define DPP_ROR4 0x124  // row_ror:4
#define DPP_ROR8 0x128  // row_ror:8

__device__ __forceinline__ void gld_lds16(const u16* g, u16* l) {
    __builtin_amdgcn_global_load_lds((__attribute__((address_space(1))) void*)g,
                                     (__attribute__((address_space(3))) void*)l,
                                     16, 0, 0);
}

// ---- fused prep: normalize f1/f2, convert banks to bf16, zero accumulators -
__global__ __launch_bounds__(256) void prep(
    const float* __restrict__ if1, const float* __restrict__ if2,
    const float* __restrict__ mb1, const float* __restrict__ mb2,
    float* __restrict__ f1f, float* __restrict__ f2f,
    u16* __restrict__ f1n, u16* __restrict__ f2n,
    u16* __restrict__ mb1n, u16* __restrict__ mb2n,
    unsigned* __restrict__ Mpack, float* __restrict__ accum)
{
    const int b = blockIdx.x, t = threadIdx.x;
    if (b == 0 && t < 8) accum[t] = 0.f;        // sums + counter
    if (b < 32) Mpack[b * 256 + t] = 0u;        // [2*NB] = 8192 for atomicMax
    if (b < 2048) {
        const int wave = t >> 6, lane = t & 63;
        const int g = b * 4 + wave;         // 0..8191
        const float* in; float* of; u16* ob; int row;
        if (g < NB) { in = if1; of = f1f; ob = f1n; row = g; }
        else        { in = if2; of = f2f; ob = f2n; row = g - NB; }
        float4 v = ((const float4*)(in + (size_t)row * ND))[lane];
        float ss = v.x*v.x + v.y*v.y + v.z*v.z + v.w*v.w;
        #pragma unroll
        for (int off = 1; off < 64; off <<= 1) ss += __shfl_xor(ss, off, 64);
        float inv = 1.0f / fmaxf(sqrtf(ss), 1e-12f);
        float4 o = make_float4(v.x*inv, v.y*inv, v.z*inv, v.w*inv);
        ((float4*)(of + (size_t)row * ND))[lane] = o;
        ushort4 bb = make_ushort4(f2bf(o.x), f2bf(o.y), f2bf(o.z), f2bf(o.w));
        ((ushort4*)(ob + (size_t)row * ND))[lane] = bb;
    } else {
        size_t i = (size_t)(b - 2048) * 256 + t;      // float4 index
        const float* in; u16* ob; size_t idx;
        if (i < (size_t)NM * 64) { in = mb1; ob = mb1n; idx = i; }
        else { in = mb2; ob = mb2n; idx = i - (size_t)NM * 64; }
        float4 v = ((const float4*)in)[idx];
        ushort4 bb = make_ushort4(f2bf(v.x), f2bf(v.y), f2bf(v.z), f2bf(v.w));
        ((ushort4*)ob)[idx] = bb;
    }
}

// ---- fused GEMM + (sum-exp, packed max/argmax) epilogue --------------------
// grid: (160 coltiles, 16 rowtiles, 2 matmuls), block 512 (8 waves, 4x2).
// Block tile 256x128; wave tile stays 64x64 (64 acc + ~64 VGPR = 128 regs
// -- the PROVEN no-spill footprint; R7/R9 both spilled when wave state
// exceeded 2048/(waves per CU)). Staging bytes/output 0.75x of 128x128.
// LDS: As 32K + Bs 16K = 48K; launch_bounds(512,4) -> 2 blocks/CU =
// 16 waves/CU (50% occupancy ceiling vs R8's 38.9%).
// XOR-swizzled LDS chunks; Z via coalesced Zpart stores; max/argmax via one
// atomicMax/row: pack=(bits(t+bias)&0xFFFFC000)|(16383-gcol).
__global__ __launch_bounds__(512, 4) void gemm_nce(
    const u16* __restrict__ f1n, const u16* __restrict__ f2n,
    const u16* __restrict__ mb1n, const u16* __restrict__ mb2n,
    const float* __restrict__ scale_ptr,
    float* __restrict__ Zpart,      // [2][CT][NB]
    unsigned* __restrict__ Mpack)   // [2][NB]
{
    __shared__ __attribute__((aligned(16))) u16 As[256 * 64];   // 32 KB
    __shared__ __attribute__((aligned(16))) u16 Bs[128 * 64];   // 16 KB
    // reduction scratch aliases As (dead after K-loop tail barrier): 4 KB
    float    (*redsum)[256] = (float(*)[256])As;
    unsigned (*redpak)[256] = (unsigned(*)[256])(As + 1024);

    const int ctile = blockIdx.x, rtile = blockIdx.y, z = blockIdx.z;
    const u16* A  = (z ? f2n : f1n) + (size_t)rtile * 256 * ND;
    const u16* Bp = (ctile < 32) ? ((z ? f1n : f2n) + (size_t)ctile * 128 * ND)
                                 : ((z ? mb1n : mb2n) + (size_t)(ctile - 32) * 128 * ND);
    const int t = threadIdx.x;
    const int wave = t >> 6, lane = t & 63;
    const int wr = wave >> 1, wc = wave & 1;       // 4 row quarters x 2 col halves
    const int lane16 = lane & 15, q = lane >> 4;
    const int srow = t >> 3;                        // 0..63 staged row
    const int cg = (t & 7) ^ (srow & 7);            // swizzled global chunk

    f32x4 acc[4][4] = {};

    #pragma unroll
    for (int kt = 0; kt < 4; ++kt) {
        const u16* ga = A  + (size_t)srow * ND + kt * 64 + cg * 8;
        const u16* gb = Bp + (size_t)srow * ND + kt * 64 + cg * 8;
        u16* la = As + t * 8;
        u16* lb = Bs + t * 8;
        #pragma unroll
        for (int ch = 0; ch < 4; ++ch)      // A: 256 rows, 64-row strides
            gld_lds16(ga + (size_t)ch * 64 * ND, la + ch * 4096);
        #pragma unroll
        for (int ch = 0; ch < 2; ++ch)      // B: 128 rows
            gld_lds16(gb + (size_t)ch * 64 * ND, lb + ch * 4096);
        __syncthreads();   // drains vmcnt (global_load_lds) before LDS reads
        #pragma unroll
        for (int kk = 0; kk < 2; ++kk) {
            const int sw = (kk * 4 + q) ^ (lane16 & 7);   // swizzled chunk slot
            bf16x8 af[4], bfr[4];
            #pragma unroll
            for (int i = 0; i < 4; ++i)
                af[i] = *(const bf16x8*)(As + (wr*64 + i*16 + lane16)*64 + sw*8);
            #pragma unroll
            for (int j = 0; j < 4; ++j)
                bfr[j] = *(const bf16x8*)(Bs + (wc*64 + j*16 + lane16)*64 + sw*8);
            #pragma unroll
            for (int i = 0; i < 4; ++i)
                #pragma unroll
                for (int j = 0; j < 4; ++j)
                    acc[i][j] = __builtin_amdgcn_mfma_f32_16x16x32_bf16(
                        af[i], bfr[j], acc[i][j], 0, 0, 0);
        }
        __syncthreads();
    }
    // As now dead as tile storage; redsum/redpak live in it from here on.

    const float scale = *scale_ptr;
    const float kl = scale * 1.44269504088896f;  // scale * log2(e)
    const float bias = kl + 1.0f;                // t+bias in [1, 2kl+1] > 0
    const bool doicel = (ctile >= 32);

    unsigned cpack[4];
    #pragma unroll
    for (int j = 0; j < 4; ++j) cpack[j] = 127 - (j * 16 + lane16);

    // C/D layout (m89/m91): col = lane&15, row = q*4 + reg (within 16x16)
    #pragma unroll
    for (int i = 0; i < 4; ++i) {
        #pragma unroll
        for (int r = 0; r < 4; ++r) {
            float t0 = kl * acc[i][0][r], t1 = kl * acc[i][1][r],
                  t2 = kl * acc[i][2][r], t3 = kl * acc[i][3][r];
            float e = (ex2(t0) + ex2(t1)) + (ex2(t2) + ex2(t3));
            e += dppf<DPP_XOR1>(e);
            e += dppf<DPP_XOR2>(e);
            e += dppf<DPP_ROR4>(e);
            e += dppf<DPP_ROR8>(e);
            unsigned p = 0;
            if (doicel) {
                unsigned p0 = (__float_as_uint(t0 + bias) & 0xFFFFFF80u) | cpack[0];
                unsigned p1 = (__float_as_uint(t1 + bias) & 0xFFFFFF80u) | cpack[1];
                unsigned p2 = (__float_as_uint(t2 + bias) & 0xFFFFFF80u) | cpack[2];
                unsigned p3 = (__float_as_uint(t3 + bias) & 0xFFFFFF80u) | cpack[3];
                p = max(max(p0, p1), max(p2, p3));
                p = max(p, dppu<DPP_XOR1>(p));
                p = max(p, dppu<DPP_XOR2>(p));
                p = max(p, dppu<DPP_ROR4>(p));
                p = max(p, dppu<DPP_ROR8>(p));
            }
            if (lane16 == 0) {
                int rl = wr*64 + i*16 + q*4 + r;   // 0..255
                redsum[wc][rl] = e;
                redpak[wc][rl] = p;
            }
        }
    }
    __syncthreads();
    if (t < 256) {
        int grow = rtile * 256 + t;
        Zpart[((size_t)z * CT + ctile) * NB + grow] = redsum[0][t] + redsum[1][t];
        if (doicel) {
            unsigned q0 = redpak[0][t], q1 = redpak[1][t];
            int c0 = 127 - (int)(q0 & 127);   // col within wc=0 half (0..63)
            int c1 = 127 - (int)(q1 & 127);
            int cb = (ctile - 32) * 128;
            unsigned g0 = (q0 & 0xFFFFC000u) | (unsigned)(16383 - (cb + c0));
            unsigned g1 = (q1 & 0xFFFFC000u) | (unsigned)(16383 - (cb + 64 + c1));
            unsigned g = g0 > g1 ? g0 : g1;   // equal-val tie -> lower gcol wins
            atomicMax(&Mpack[z * NB + grow], g);
        }
    }
}

// ---- finalize: Z-reduce + decode argmax + gather + MSE/CE + combine --------
// 256 blocks x 256 threads: 16 rows/block.
__global__ __launch_bounds__(256) void finalize4(
    const float* __restrict__ Zpart, const unsigned* __restrict__ Mpack,
    const float* __restrict__ f1f, const float* __restrict__ f2f,
    const float* __restrict__ mb1, const float* __restrict__ mb2,
    const float* __restrict__ scale_ptr, float* __restrict__ accum,
    float* __restrict__ out)
{
    __shared__ float zp[2][16][16];   // [z][cidx][row_l]
    __shared__ float Zr[2][16];
    __shared__ float lds5[16][5];
    const int t = threadIdx.x, g = t >> 4, l16 = t & 15;
    const int base = blockIdx.x * 16;

    // Phase A: Z partial sums, coalesced (lanes along rows)
    {
        const int row_l = t & 15, cidx = t >> 4;
        #pragma unroll
        for (int z = 0; z < 2; ++z) {
            float s = 0.f;
            #pragma unroll
            for (int c = cidx * 10; c < cidx * 10 + 10; ++c)
                s += Zpart[((size_t)z * CT + c) * NB + base + row_l];
            zp[z][cidx][row_l] = s;
        }
    }
    __syncthreads();
    if (t < 32) {
        int z = t >> 4, rl = t & 15;
        float s = 0.f;
        #pragma unroll
        for (int k = 0; k < 16; ++k) s += zp[z][k][rl];
        Zr[z][rl] = s;
    }
    __syncthreads();

    const int row = base + g;
    const float scale = *scale_ptr;
    const float kl = scale * 1.44269504088896f;
    const float bias = kl + 1.0f;

    unsigned mp1 = Mpack[row], mp2 = Mpack[NB + row];
    int a1 = 16383 - (int)(mp1 & 16383u);
    int a2 = 16383 - (int)(mp2 & 16383u);
    float m1 = (__uint_as_float(mp1 & 0xFFFFC000u) - bias) / kl;
    float m2 = (__uint_as_float(mp2 & 0xFFFFC000u) - bias) / kl;

    const float4* x1p = (const float4*)(f1f + (size_t)row * ND);
    const float4* x2p = (const float4*)(f2f + (size_t)row * ND);
    const float4* y1p = (const float4*)(mb2 + (size_t)a1 * ND);
    const float4* y2p = (const float4*)(mb1 + (size_t)a2 * ND);
    float d = 0.f, sq1 = 0.f, sq2 = 0.f;
    #pragma unroll
    for (int k = 0; k < 4; ++k) {
        int idx = k * 16 + l16;
        float4 x1 = x1p[idx], x2 = x2p[idx], y1 = y1p[idx], y2 = y2p[idx];
        d += x1.x*x2.x + x1.y*x2.y + x1.z*x2.z + x1.w*x2.w;
        float dx = x1.x-y1.x, dy = x1.y-y1.y, dz = x1.z-y1.z, dw = x1.w-y1.w;
        sq1 += dx*dx + dy*dy + dz*dz + dw*dw;
        dx = x2.x-y2.x; dy = x2.y-y2.y; dz = x2.z-y2.z; dw = x2.w-y2.w;
        sq2 += dx*dx + dy*dy + dz*dz + dw*dw;
    }
    #pragma unroll
    for (int off = 1; off < 16; off <<= 1) {
        d   += __shfl_xor(d,   off, 16);
        sq1 += __shfl_xor(sq1, off, 16);
        sq2 += __shfl_xor(sq2, off, 16);
    }
    if (l16 == 0) {
        bool k1 = m1 > 0.2f, k2 = m2 > 0.2f;
        lds5[g][0] = logf(Zr[0][g]) + logf(Zr[1][g]) - 2.f * scale * d;
        lds5[g][1] = k1 ? sq1 : 0.f;
        lds5[g][2] = k1 ? 1.f : 0.f;
        lds5[g][3] = k2 ? sq2 : 0.f;
        lds5[g][4] = k2 ? 1.f : 0.f;
    }
    __syncthreads();
    if (t < 5) {
        float s = 0.f;
        #pragma unroll
        for (int r = 0; r < 16; ++r) s += lds5[r][t];
        atomicAdd(&accum[t], s);
    }
    __syncthreads();
    if (t == 0) {
        __threadfence();
        int old = atomicAdd((int*)(accum + 5), 1);
        if (old == (int)gridDim.x - 1) {        // last block: combine
            __threadfence();
            float a0 = atomicAdd(&accum[0], 0.f);
            float a1v = atomicAdd(&accum[1], 0.f);
            float a2v = atomicAdd(&accum[2], 0.f);
            float a3v = atomicAdd(&accum[3], 0.f);
            float a4v = atomicAdd(&accum[4], 0.f);
            float nce = 0.5f * a0 / (float)NB;
            float icel1 = a2v > 0.f ? a1v / (a2v * (float)ND) : 0.f;
            float icel2 = a4v > 0.f ? a3v / (a4v * (float)ND) : 0.f;
            out[0] = nce + 0.25f * (icel1 + icel2);   // LAMBDA_ICEL = 0.5
        }
    }
}

extern "C" void kernel_launch(void* const* d_in, const int* in_sizes, int n_in,
                              void* d_out, int out_size, void* d_ws, size_t ws_size,
                              hipStream_t stream) {
    const float* if1   = (const float*)d_in[0];
    const float* if2   = (const float*)d_in[1];
    const float* scale = (const float*)d_in[2];
    const float* mb1   = (const float*)d_in[3];
    const float* mb2   = (const float*)d_in[4];
    float* out = (float*)d_out;

    unsigned char* w = (unsigned char*)d_ws;
    size_t off = 0;
    auto alloc = [&](size_t bytes) {
        void* p = w + off;
        off += (bytes + 255) & ~(size_t)255;
        return p;
    };
    u16*      f1n   = (u16*)     alloc((size_t)NB * ND * 2);
    u16*      f2n   = (u16*)     alloc((size_t)NB * ND * 2);
    u16*      mb1n  = (u16*)     alloc((size_t)NM * ND * 2);
    u16*      mb2n  = (u16*)     alloc((size_t)NM * ND * 2);
    float*    f1f   = (float*)   alloc((size_t)NB * ND * 4);
    float*    f2f   = (float*)   alloc((size_t)NB * ND * 4);
    float*    Zpart = (float*)   alloc((size_t)2 * CT * NB * 4);
    unsigned* Mpack = (unsigned*)alloc((size_t)2 * NB * 4);
    float*    accum = (float*)   alloc(256);

    prep<<<dim3(10240), 256, 0, stream>>>(if1, if2, mb1, mb2,
                                          f1f, f2f, f1n, f2n, mb1n, mb2n,
                                          Mpack, accum);
    gemm_nce<<<dim3(CT, RT, 2), 512, 0, stream>>>(f1n, f2n, mb1n, mb2n, scale,
                                                  Zpart, Mpack);
    finalize4<<<dim3(NB / 16), 256, 0, stream>>>(Zpart, Mpack,
                                                 f1f, f2f, mb1, mb2, scale,
                                                 accum, out);
}

// Round 12
// 178.021 us; speedup vs baseline: 1.3205x; 1.1778x over previous
//
#include <hip/hip_runtime.h>
#include <hip/hip_bf16.h>

typedef unsigned char u8;
typedef float f32x4 __attribute__((ext_vector_type(4)));
typedef int i32x4 __attribute__((ext_vector_type(4)));
typedef int i32x8 __attribute__((ext_vector_type(8)));

#define NB 4096     // batch rows
#define NM 16384    // memory bank rows
#define ND 256      // feature dim (K)
#define CT 160      // col tiles (20480 / 128)
#define RT 32       // row tiles (4096 / 128)

__device__ __forceinline__ float ex2(float x) {
#if __has_builtin(__builtin_amdgcn_exp2f)
    return __builtin_amdgcn_exp2f(x);   // single v_exp_f32
#else
    return exp2f(x);
#endif
}

// float4 -> 4 packed OCP e4m3 bytes (v_cvt_pk_fp8_f32, gfx940+)
__device__ __forceinline__ int f4_to_fp8x4(float4 v) {
    int r = __builtin_amdgcn_cvt_pk_fp8_f32(v.x, v.y, 0, false);   // bytes 0,1
    r = __builtin_amdgcn_cvt_pk_fp8_f32(v.z, v.w, r, true);        // bytes 2,3
    return r;
}

// DPP lane moves within a row of 16 (our reduction group = lane16, q = DPP row)
template<int C>
__device__ __forceinline__ float dppf(float x) {
    int v = __float_as_int(x);
    return __int_as_float(__builtin_amdgcn_update_dpp(v, v, C, 0xF, 0xF, false));
}
template<int C>
__device__ __forceinline__ unsigned dppu(unsigned x) {
    return (unsigned)__builtin_amdgcn_update_dpp((int)x, (int)x, C, 0xF, 0xF, false);
}
#define DPP_XOR1 0xB1   // quad_perm [1,0,3,2]
#define DPP_XOR2 0x4E   // quad_perm [2,3,0,1]
#define DPP_ROR4 0x124  // row_ror:4
#define DPP_ROR8 0x128  // row_ror:8

__device__ __forceinline__ void gld_lds16(const u8* g, u8* l) {
    __builtin_amdgcn_global_load_lds((__attribute__((address_space(1))) void*)g,
                                     (__attribute__((address_space(3))) void*)l,
                                     16, 0, 0);
}

// ---- fused prep: normalize f1/f2 (fp32 + fp8), convert banks to fp8 --------
// blocks 0..2047: norm (4 rows each). blocks 2048..10239: bank conversion
// (8192 blocks x 256 threads = 2,097,152 float4s = BOTH banks; R11 launched
// only 4096 conv blocks -> mb2n stayed 0xAA poison -> absmax 0.5).
__global__ __launch_bounds__(256) void prep(
    const float* __restrict__ if1, const float* __restrict__ if2,
    const float* __restrict__ mb1, const float* __restrict__ mb2,
    float* __restrict__ f1f, float* __restrict__ f2f,
    u8* __restrict__ f1n, u8* __restrict__ f2n,
    u8* __restrict__ mb1n, u8* __restrict__ mb2n,
    unsigned* __restrict__ Mpack, float* __restrict__ accum)
{
    const int b = blockIdx.x, t = threadIdx.x;
    if (b == 0 && t < 8) accum[t] = 0.f;        // sums + counter
    if (b < 32) Mpack[b * 256 + t] = 0u;        // [2*NB] = 8192 for atomicMax
    if (b < 2048) {
        const int wave = t >> 6, lane = t & 63;
        const int g = b * 4 + wave;         // 0..8191
        const float* in; float* of; u8* ob; int row;
        if (g < NB) { in = if1; of = f1f; ob = f1n; row = g; }
        else        { in = if2; of = f2f; ob = f2n; row = g - NB; }
        float4 v = ((const float4*)(in + (size_t)row * ND))[lane];
        float ss = v.x*v.x + v.y*v.y + v.z*v.z + v.w*v.w;
        #pragma unroll
        for (int off = 1; off < 64; off <<= 1) ss += __shfl_xor(ss, off, 64);
        float inv = 1.0f / fmaxf(sqrtf(ss), 1e-12f);
        float4 o = make_float4(v.x*inv, v.y*inv, v.z*inv, v.w*inv);
        ((float4*)(of + (size_t)row * ND))[lane] = o;
        ((int*)ob)[row * 64 + lane] = f4_to_fp8x4(o);
    } else {
        size_t i = (size_t)(b - 2048) * 256 + t;      // float4 index, 0..2M
        const float* in; u8* ob; size_t idx;
        if (i < (size_t)NM * 64) { in = mb1; ob = mb1n; idx = i; }
        else { in = mb2; ob = mb2n; idx = i - (size_t)NM * 64; }
        float4 v = ((const float4*)in)[idx];
        ((int*)ob)[idx] = f4_to_fp8x4(v);
    }
}

// ---- fused GEMM (MX-fp8 K=128) + (sum-exp, packed max/argmax) epilogue -----
// grid: (160 coltiles, 32 rowtiles, 2 matmuls), block 256 (4 waves, 2x2).
// Block tile 128x128, fp8 e4m3 inputs, mfma_scale_f32_16x16x128_f8f6f4 with
// unit scales (0x7F = e8m0 1.0). K staged in 2 chunks of 128 B/row.
// LDS rows = 128 B = 8 x 16B chunks, XOR-swizzled: slot cs holds global
// chunk cs^(row&7); fragment (32 B = chunks 2q,2q+1) -> 2 ds_read_b128.
// launch_bounds(256,3): 170-reg budget (64 acc + 32 Bfrag + 8 Afrag + misc);
// (256,4)'s 128 budget would spill (R7/R9 lesson). LDS 32 KB.
// Z via coalesced Zpart stores; max/argmax via one atomicMax/row.
__global__ __launch_bounds__(256, 3) void gemm_nce(
    const u8* __restrict__ f1n, const u8* __restrict__ f2n,
    const u8* __restrict__ mb1n, const u8* __restrict__ mb2n,
    const float* __restrict__ scale_ptr,
    float* __restrict__ Zpart,      // [2][CT][NB]
    unsigned* __restrict__ Mpack)   // [2][NB]
{
    __shared__ __attribute__((aligned(16))) u8 As[128 * 128];   // 16 KB
    __shared__ __attribute__((aligned(16))) u8 Bs[128 * 128];   // 16 KB
    // reduction scratch aliases As (dead after K-loop tail barrier): 2 KB
    float    (*redsum)[128] = (float(*)[128])As;
    unsigned (*redpak)[128] = (unsigned(*)[128])(As + 1024);

    const int ctile = blockIdx.x, rtile = blockIdx.y, z = blockIdx.z;
    const u8* A  = (z ? f2n : f1n) + (size_t)rtile * 128 * ND;
    const u8* Bp = (ctile < 32) ? ((z ? f1n : f2n) + (size_t)ctile * 128 * ND)
                                 : ((z ? mb1n : mb2n) + (size_t)(ctile - 32) * 128 * ND);
    const int t = threadIdx.x;
    const int wave = t >> 6, lane = t & 63;
    const int wr = wave >> 1, wc = wave & 1;
    const int lane16 = lane & 15, q = lane >> 4;
    const int srow = t >> 3;                        // 0..31 staged row
    const int cg = (t & 7) ^ (srow & 7);            // swizzled global chunk

    f32x4 acc[4][4] = {};

    #pragma unroll
    for (int kt = 0; kt < 2; ++kt) {
        const u8* ga = A  + (size_t)srow * ND + kt * 128 + cg * 16;
        const u8* gb = Bp + (size_t)srow * ND + kt * 128 + cg * 16;
        u8* la = As + t * 16;
        u8* lb = Bs + t * 16;
        #pragma unroll
        for (int ch = 0; ch < 4; ++ch) {    // 128 rows in 32-row strides
            gld_lds16(ga + (size_t)ch * 32 * ND, la + ch * 4096);
            gld_lds16(gb + (size_t)ch * 32 * ND, lb + ch * 4096);
        }
        __syncthreads();   // drains vmcnt (global_load_lds) before LDS reads
        {
            i32x8 b8[4];
            #pragma unroll
            for (int j = 0; j < 4; ++j) {
                int rb = wc*64 + j*16 + lane16;
                const u8* pb = Bs + rb * 128;
                int s0 = (2*q) ^ (rb & 7);
                i32x4 lo = *(const i32x4*)(pb + s0*16);
                i32x4 hi = *(const i32x4*)(pb + (s0^1)*16);
                b8[j] = (i32x8){lo[0],lo[1],lo[2],lo[3],hi[0],hi[1],hi[2],hi[3]};
            }
            #pragma unroll
            for (int i = 0; i < 4; ++i) {
                int ra = wr*64 + i*16 + lane16;
                const u8* pa = As + ra * 128;
                int s0 = (2*q) ^ (ra & 7);
                i32x4 lo = *(const i32x4*)(pa + s0*16);
                i32x4 hi = *(const i32x4*)(pa + (s0^1)*16);
                i32x8 a8 = (i32x8){lo[0],lo[1],lo[2],lo[3],hi[0],hi[1],hi[2],hi[3]};
                #pragma unroll
                for (int j = 0; j < 4; ++j)
                    acc[i][j] = __builtin_amdgcn_mfma_scale_f32_16x16x128_f8f6f4(
                        a8, b8[j], acc[i][j], 0, 0,
                        0, 0x7F7F7F7F, 0, 0x7F7F7F7F);   // unit e8m0 scales
            }
        }
        __syncthreads();
    }
    // As now dead as tile storage; redsum/redpak live in it from here on.

    const float scale = *scale_ptr;
    const float kl = scale * 1.44269504088896f;  // scale * log2(e)
    const float bias = kl + 1.0f;                // t+bias in [1, 2kl+1] > 0
    const bool doicel = (ctile >= 32);

    unsigned cpack[4];
    #pragma unroll
    for (int j = 0; j < 4; ++j) cpack[j] = 127 - (j * 16 + lane16);

    // C/D layout (m89/m91, dtype-independent): col = lane&15, row = q*4 + r
    #pragma unroll
    for (int i = 0; i < 4; ++i) {
        #pragma unroll
        for (int r = 0; r < 4; ++r) {
            float t0 = kl * acc[i][0][r], t1 = kl * acc[i][1][r],
                  t2 = kl * acc[i][2][r], t3 = kl * acc[i][3][r];
            float e = (ex2(t0) + ex2(t1)) + (ex2(t2) + ex2(t3));
            e += dppf<DPP_XOR1>(e);
            e += dppf<DPP_XOR2>(e);
            e += dppf<DPP_ROR4>(e);
            e += dppf<DPP_ROR8>(e);
            unsigned p = 0;
            if (doicel) {
                unsigned p0 = (__float_as_uint(t0 + bias) & 0xFFFFFF80u) | cpack[0];
                unsigned p1 = (__float_as_uint(t1 + bias) & 0xFFFFFF80u) | cpack[1];
                unsigned p2 = (__float_as_uint(t2 + bias) & 0xFFFFFF80u) | cpack[2];
                unsigned p3 = (__float_as_uint(t3 + bias) & 0xFFFFFF80u) | cpack[3];
                p = max(max(p0, p1), max(p2, p3));
                p = max(p, dppu<DPP_XOR1>(p));
                p = max(p, dppu<DPP_XOR2>(p));
                p = max(p, dppu<DPP_ROR4>(p));
                p = max(p, dppu<DPP_ROR8>(p));
            }
            if (lane16 == 0) {
                int rl = wr*64 + i*16 + q*4 + r;
                redsum[wc][rl] = e;
                redpak[wc][rl] = p;
            }
        }
    }
    __syncthreads();
    if (t < 128) {
        int grow = rtile * 128 + t;
        Zpart[((size_t)z * CT + ctile) * NB + grow] = redsum[0][t] + redsum[1][t];
        if (doicel) {
            unsigned q0 = redpak[0][t], q1 = redpak[1][t];
            int c0 = 127 - (int)(q0 & 127);   // col within wc=0 half (0..63)
            int c1 = 127 - (int)(q1 & 127);
            int cb = (ctile - 32) * 128;
            unsigned g0 = (q0 & 0xFFFFC000u) | (unsigned)(16383 - (cb + c0));
            unsigned g1 = (q1 & 0xFFFFC000u) | (unsigned)(16383 - (cb + 64 + c1));
            unsigned g = g0 > g1 ? g0 : g1;   // equal-val tie -> lower gcol wins
            atomicMax(&Mpack[z * NB + grow], g);
        }
    }
}

// ---- finalize: Z-reduce + decode argmax + gather + MSE/CE + combine --------
// 256 blocks x 256 threads: 16 rows/block. (fp32 banks -> exact MSE/diag.)
__global__ __launch_bounds__(256) void finalize4(
    const float* __restrict__ Zpart, const unsigned* __restrict__ Mpack,
    const float* __restrict__ f1f, const float* __restrict__ f2f,
    const float* __restrict__ mb1, const float* __restrict__ mb2,
    const float* __restrict__ scale_ptr, float* __restrict__ accum,
    float* __restrict__ out)
{
    __shared__ float zp[2][16][16];   // [z][cidx][row_l]
    __shared__ float Zr[2][16];
    __shared__ float lds5[16][5];
    const int t = threadIdx.x, g = t >> 4, l16 = t & 15;
    const int base = blockIdx.x * 16;

    // Phase A: Z partial sums, coalesced (lanes along rows)
    {
        const int row_l = t & 15, cidx = t >> 4;
        #pragma unroll
        for (int z = 0; z < 2; ++z) {
            float s = 0.f;
            #pragma unroll
            for (int c = cidx * 10; c < cidx * 10 + 10; ++c)
                s += Zpart[((size_t)z * CT + c) * NB + base + row_l];
            zp[z][cidx][row_l] = s;
        }
    }
    __syncthreads();
    if (t < 32) {
        int z = t >> 4, rl = t & 15;
        float s = 0.f;
        #pragma unroll
        for (int k = 0; k < 16; ++k) s += zp[z][k][rl];
        Zr[z][rl] = s;
    }
    __syncthreads();

    const int row = base + g;
    const float scale = *scale_ptr;
    const float kl = scale * 1.44269504088896f;
    const float bias = kl + 1.0f;

    unsigned mp1 = Mpack[row], mp2 = Mpack[NB + row];
    int a1 = 16383 - (int)(mp1 & 16383u);
    int a2 = 16383 - (int)(mp2 & 16383u);
    float m1 = (__uint_as_float(mp1 & 0xFFFFC000u) - bias) / kl;
    float m2 = (__uint_as_float(mp2 & 0xFFFFC000u) - bias) / kl;

    const float4* x1p = (const float4*)(f1f + (size_t)row * ND);
    const float4* x2p = (const float4*)(f2f + (size_t)row * ND);
    const float4* y1p = (const float4*)(mb2 + (size_t)a1 * ND);
    const float4* y2p = (const float4*)(mb1 + (size_t)a2 * ND);
    float d = 0.f, sq1 = 0.f, sq2 = 0.f;
    #pragma unroll
    for (int k = 0; k < 4; ++k) {
        int idx = k * 16 + l16;
        float4 x1 = x1p[idx], x2 = x2p[idx], y1 = y1p[idx], y2 = y2p[idx];
        d += x1.x*x2.x + x1.y*x2.y + x1.z*x2.z + x1.w*x2.w;
        float dx = x1.x-y1.x, dy = x1.y-y1.y, dz = x1.z-y1.z, dw = x1.w-y1.w;
        sq1 += dx*dx + dy*dy + dz*dz + dw*dw;
        dx = x2.x-y2.x; dy = x2.y-y2.y; dz = x2.z-y2.z; dw = x2.w-y2.w;
        sq2 += dx*dx + dy*dy + dz*dz + dw*dw;
    }
    #pragma unroll
    for (int off = 1; off < 16; off <<= 1) {
        d   += __shfl_xor(d,   off, 16);
        sq1 += __shfl_xor(sq1, off, 16);
        sq2 += __shfl_xor(sq2, off, 16);
    }
    if (l16 == 0) {
        bool k1 = m1 > 0.2f, k2 = m2 > 0.2f;
        lds5[g][0] = logf(Zr[0][g]) + logf(Zr[1][g]) - 2.f * scale * d;
        lds5[g][1] = k1 ? sq1 : 0.f;
        lds5[g][2] = k1 ? 1.f : 0.f;
        lds5[g][3] = k2 ? sq2 : 0.f;
        lds5[g][4] = k2 ? 1.f : 0.f;
    }
    __syncthreads();
    if (t < 5) {
        float s = 0.f;
        #pragma unroll
        for (int r = 0; r < 16; ++r) s += lds5[r][t];
        atomicAdd(&accum[t], s);
    }
    __syncthreads();
    if (t == 0) {
        __threadfence();
        int old = atomicAdd((int*)(accum + 5), 1);
        if (old == (int)gridDim.x - 1) {        // last block: combine
            __threadfence();
            float a0 = atomicAdd(&accum[0], 0.f);
            float a1v = atomicAdd(&accum[1], 0.f);
            float a2v = atomicAdd(&accum[2], 0.f);
            float a3v = atomicAdd(&accum[3], 0.f);
            float a4v = atomicAdd(&accum[4], 0.f);
            float nce = 0.5f * a0 / (float)NB;
            float icel1 = a2v > 0.f ? a1v / (a2v * (float)ND) : 0.f;
            float icel2 = a4v > 0.f ? a3v / (a4v * (float)ND) : 0.f;
            out[0] = nce + 0.25f * (icel1 + icel2);   // LAMBDA_ICEL = 0.5
        }
    }
}

extern "C" void kernel_launch(void* const* d_in, const int* in_sizes, int n_in,
                              void* d_out, int out_size, void* d_ws, size_t ws_size,
                              hipStream_t stream) {
    const float* if1   = (const float*)d_in[0];
    const float* if2   = (const float*)d_in[1];
    const float* scale = (const float*)d_in[2];
    const float* mb1   = (const float*)d_in[3];
    const float* mb2   = (const float*)d_in[4];
    float* out = (float*)d_out;

    unsigned char* w = (unsigned char*)d_ws;
    size_t off = 0;
    auto alloc = [&](size_t bytes) {
        void* p = w + off;
        off += (bytes + 255) & ~(size_t)255;
        return p;
    };
    u8*       f1n   = (u8*)      alloc((size_t)NB * ND);
    u8*       f2n   = (u8*)      alloc((size_t)NB * ND);
    u8*       mb1n  = (u8*)      alloc((size_t)NM * ND);
    u8*       mb2n  = (u8*)      alloc((size_t)NM * ND);
    float*    f1f   = (float*)   alloc((size_t)NB * ND * 4);
    float*    f2f   = (float*)   alloc((size_t)NB * ND * 4);
    float*    Zpart = (float*)   alloc((size_t)2 * CT * NB * 4);
    unsigned* Mpack = (unsigned*)alloc((size_t)2 * NB * 4);
    float*    accum = (float*)   alloc(256);

    prep<<<dim3(10240), 256, 0, stream>>>(if1, if2, mb1, mb2,
                                          f1f, f2f, f1n, f2n, mb1n, mb2n,
                                          Mpack, accum);
    gemm_nce<<<dim3(CT, RT, 2), 256, 0, stream>>>(f1n, f2n, mb1n, mb2n, scale,
                                                  Zpart, Mpack);
    finalize4<<<dim3(NB / 16), 256, 0, stream>>>(Zpart, Mpack,
                                                 f1f, f2f, mb1, mb2, scale,
                                                 accum, out);
}